// Round 17
// baseline (581.921 us; speedup 1.0000x reference)
//
#include <hip/hip_runtime.h>

#define NN 100000
#define NE 1000000
#define NG 256
#define HD 146
#define SP 152          // padded row stride for hh (f16): 19 x f16x8
#define EPSF 1e-5f
#define NRB 6250        // NN/16 row-blocks (exact)
#define GB 782          // MFMA grid = ceil(NRB/8)

// binned CSR build
#define NBIN 196        // ceil(NN/512)
#define CHUNK 2048
#define NCH 489         // ceil(NE/2048)
#define LCSRC 6144      // per-bin LDS CSR capacity
#define PREPB 350       // prep blocks: ceil(89408/256)

typedef _Float16 f16;
typedef f16 f16x8 __attribute__((ext_vector_type(8)));
typedef f16 f16x4 __attribute__((ext_vector_type(4)));
typedef float f32x4 __attribute__((ext_vector_type(4)));

// ---------------- k_A = p1 histograms (blocks<NCH) + one-shot prep ----------------
__global__ __launch_bounds__(256) void k_A(const int* __restrict__ src,
    const int* __restrict__ dst, int* __restrict__ bhD, int* __restrict__ bhS,
    const float* __restrict__ W_e, const float* __restrict__ W1,
    const float* __restrict__ W2, const float* __restrict__ W3,
    const float* __restrict__ b_e, const float* __restrict__ b1,
    const float* __restrict__ b2, const float* __restrict__ b3,
    f16* __restrict__ WtE, f16* __restrict__ Wt, float* __restrict__ bp,
    const int* __restrict__ gid, int* __restrict__ gb,
    float* __restrict__ stsum3, int* __restrict__ rcnt) {
  __shared__ int hd[NBIN], hs[NBIN];
  int t = threadIdx.x;
  if (blockIdx.x < NCH) {
    if (t < NBIN) { hd[t] = 0; hs[t] = 0; }
    __syncthreads();
    int base = blockIdx.x * CHUNK;
#pragma unroll
    for (int i = 0; i < 8; ++i) {
      int e = base + i * 256 + t;
      if (e < NE) {
        atomicAdd(&hd[dst[e] >> 9], 1);
        atomicAdd(&hs[src[e] >> 9], 1);
      }
    }
    __syncthreads();
    if (t < NBIN) {
      bhD[t * NCH + blockIdx.x] = hd[t];
      bhS[t * NCH + blockIdx.x] = hs[t];
    }
    return;
  }
  int idx = (blockIdx.x - NCH) * 256 + t;
  if (idx < 10240) {                       // W_e [64][146] -> [10 cb][8 kg][16][8]
    int j = idx & 7, pos = (idx >> 3) & 15;
    int rem = idx >> 7;
    int kg = rem & 7, cb = rem >> 3;
    int c = cb * 16 + pos, k = kg * 8 + j;
    WtE[idx] = (c < HD) ? (f16)W_e[k * HD + c] : (f16)0;
  } else if (idx < 87040) {                // W_l [146][146] -> [10 cb][20 kg][16][8] x3
    int i2 = idx - 10240;
    int l = i2 / 25600, m = i2 % 25600;
    const float* W = (l == 0) ? W1 : (l == 1) ? W2 : W3;
    int j = m & 7, pos = (m >> 3) & 15;
    int rem = m >> 7;
    int kg = rem % 20, cb = rem / 20;
    int c = cb * 16 + pos, k = kg * 8 + j;
    Wt[i2] = (k < HD && c < HD) ? (f16)W[k * HD + c] : (f16)0;
  } else if (idx < 87680) {                // biases padded to 160, x4
    int i2 = idx - 87040;
    int which = i2 / 160, tt = i2 % 160;
    const float* b = (which == 0) ? b_e : (which == 1) ? b1 : (which == 2) ? b2 : b3;
    bp[i2] = (tt < HD) ? b[tt] : 0.f;
  } else if (idx < 88192) {                // graph row bounds (gid sorted)
    int g = idx - 87680;
    if (g <= NG) {
      int lo = 0, hi = NN;
      while (lo < hi) {
        int m = (lo + hi) >> 1;
        if (gid[m] < g) lo = m + 1; else hi = m;
      }
      gb[g] = lo;
    }
  } else if (idx < 89152) {                // BN stat accumulators, 3 x 320
    stsum3[idx - 88192] = 0.f;
  } else if (idx < 89408) {                // readout last-block counters
    rcnt[idx - 89152] = 0;
  }
}

// ---------------- pass 2: per-bin exclusive scan over blocks ----------------
__global__ __launch_bounds__(512) void k_p2(int* __restrict__ bhD, int* __restrict__ bhS,
                                            int* __restrict__ btotD, int* __restrict__ btotS) {
  __shared__ int sm[512];
  int B = blockIdx.x % NBIN;
  bool isS = blockIdx.x >= NBIN;
  int* bh = isS ? bhS : bhD;
  int* btot = isS ? btotS : btotD;
  int t = threadIdx.x;
  int v = (t < NCH) ? bh[B * NCH + t] : 0;
  sm[t] = v; __syncthreads();
  for (int o = 1; o < 512; o <<= 1) {
    int a = (t >= o) ? sm[t - o] : 0;
    __syncthreads();
    sm[t] += a;
    __syncthreads();
  }
  if (t < NCH) bh[B * NCH + t] = sm[t] - v;
  if (t == 511) btot[B] = sm[511];
}

// ---------------- k_B = p4 scatter w/ inline base scans (blocks<NCH) + membed ----------
__global__ __launch_bounds__(256) void k_B(const int* __restrict__ src,
    const int* __restrict__ dst, const int* __restrict__ bhD, const int* __restrict__ bhS,
    const int* __restrict__ btotD, const int* __restrict__ btotS,
    int* __restrict__ baseD, int* __restrict__ baseS,
    int2* __restrict__ binD, int* __restrict__ binS,
    const float* __restrict__ X, const f16* __restrict__ WtE,
    const float* __restrict__ bp, f16* __restrict__ Hh) {
  __shared__ int curD[NBIN], curS[NBIN], sm2[256];
  __shared__ __align__(16) f16 As[8 * 512];
  __shared__ __align__(16) f16 Ws[10 * 512];
  int t = threadIdx.x;

  if (blockIdx.x < NCH) {
    // inline exclusive scan of btotD -> per-block cursors
    int v = (t < NBIN) ? btotD[t] : 0;
    sm2[t] = v; __syncthreads();
    for (int o = 1; o < 256; o <<= 1) {
      int a = (t >= o) ? sm2[t - o] : 0;
      __syncthreads();
      sm2[t] += a;
      __syncthreads();
    }
    int bD = sm2[t] - v;
    if (t < NBIN) {
      curD[t] = bD + bhD[t * NCH + blockIdx.x];
      if (blockIdx.x == 0) baseD[t] = bD;
    }
    __syncthreads();
    v = (t < NBIN) ? btotS[t] : 0;
    sm2[t] = v; __syncthreads();
    for (int o = 1; o < 256; o <<= 1) {
      int a = (t >= o) ? sm2[t - o] : 0;
      __syncthreads();
      sm2[t] += a;
      __syncthreads();
    }
    int bS = sm2[t] - v;
    if (t < NBIN) {
      curS[t] = bS + bhS[t * NCH + blockIdx.x];
      if (blockIdx.x == 0) baseS[t] = bS;
    }
    __syncthreads();
    int base = blockIdx.x * CHUNK;
#pragma unroll
    for (int i = 0; i < 8; ++i) {
      int e = base + i * 256 + t;
      if (e < NE) {
        int d = dst[e], s = src[e];
        int pD = atomicAdd(&curD[d >> 9], 1);
        binD[pD] = make_int2(d, s);
        int pS = atomicAdd(&curS[s >> 9], 1);
        binS[pS] = s;
      }
    }
    return;
  }

  // ---- membed: hh = f16(X) @ WtE + bp ----
  int w = t >> 6, l = t & 63;
  int wr = w >> 1, wc = w & 1;
  int l15 = l & 15, l4 = l >> 4;
  int RB0 = (blockIdx.x - NCH) * 8;

  f32x4 acc[4][5];
#pragma unroll
  for (int i = 0; i < 4; ++i)
#pragma unroll
    for (int j = 0; j < 5; ++j) acc[i][j] = (f32x4)0.f;

#pragma unroll 1
  for (int s = 0; s < 2; ++s) {
    __syncthreads();
#pragma unroll
    for (int u = 0; u < 2; ++u) {
      int i = t + u * 256;
      int rb = i >> 6, p = i & 63;
      int kg = 4 * s + (p >> 4), pos = p & 15;
      int row = (RB0 + rb) * 16 + pos;
      f16x8 v = (f16x8)(f16)0;
      if (row < NN) {
        const float4* xp = (const float4*)(X + (size_t)row * 64 + kg * 8);
        float4 a = xp[0], b = xp[1];
        v[0] = (f16)a.x; v[1] = (f16)a.y; v[2] = (f16)a.z; v[3] = (f16)a.w;
        v[4] = (f16)b.x; v[5] = (f16)b.y; v[6] = (f16)b.z; v[7] = (f16)b.w;
      }
      *(f16x8*)(As + rb * 512 + p * 8) = v;
    }
#pragma unroll
    for (int u = 0; u < 3; ++u) {
      int m = t + u * 256;
      if (m < 640) {
        int cb = m >> 6, p = m & 63;
        f16x8 v = *(const f16x8*)(WtE + ((size_t)cb * 8 + 4 * s) * 128 + p * 8);
        *(f16x8*)(Ws + cb * 512 + p * 8) = v;
      }
    }
    __syncthreads();

    f16x8 af[4], bf[5];
#pragma unroll
    for (int i = 0; i < 4; ++i)
      af[i] = *(const f16x8*)(As + (wr * 4 + i) * 512 + l4 * 128 + l15 * 8);
#pragma unroll
    for (int j = 0; j < 5; ++j)
      bf[j] = *(const f16x8*)(Ws + (wc * 5 + j) * 512 + l4 * 128 + l15 * 8);
#pragma unroll
    for (int i = 0; i < 4; ++i)
#pragma unroll
      for (int j = 0; j < 5; ++j)
        acc[i][j] = __builtin_amdgcn_mfma_f32_16x16x32_f16(af[i], bf[j], acc[i][j], 0, 0, 0);
  }

  int colbase = wc * 80;
  int rowbase = RB0 * 16 + wr * 64;
#pragma unroll
  for (int i = 0; i < 4; ++i) {
#pragma unroll
    for (int r = 0; r < 4; ++r) {
      int row = rowbase + i * 16 + l4 * 4 + r;
      if (row < NN) {
#pragma unroll
        for (int j = 0; j < 5; ++j) {
          int col = colbase + j * 16 + l15;
          float v = acc[i][j][r] + bp[col];
          if (col < HD) Hh[(size_t)row * SP + col] = (f16)v;
          else if (col < SP) Hh[(size_t)row * SP + col] = (f16)0;
        }
      }
    }
  }
}

// ---------------- pass 5+6 merged: per-bin CSR (dst) / out-degree (src) ----------------
__global__ __launch_bounds__(512) void k_p56(const int2* __restrict__ binD,
                                             const int* __restrict__ baseD,
                                             const int* __restrict__ binS,
                                             const int* __restrict__ baseS,
                                             int* __restrict__ offs, int* __restrict__ csr,
                                             float* __restrict__ nd, float* __restrict__ ns) {
  __shared__ int lcnt[512];
  __shared__ int sm[512];
  __shared__ int lcsr[LCSRC];
  int t = threadIdx.x;

  if (blockIdx.x >= NBIN) {
    int bin = blockIdx.x - NBIN;
    int n0 = bin << 9;
    int e0 = baseS[bin];
    int e1 = (bin == NBIN - 1) ? NE : baseS[bin + 1];
    int m = e1 - e0;
    lcnt[t] = 0; __syncthreads();
    for (int k = t; k < m; k += 512) atomicAdd(&lcnt[binS[e0 + k] & 511], 1);
    __syncthreads();
    if (n0 + t < NN) ns[n0 + t] = rsqrtf(fmaxf((float)lcnt[t], 1.f));
    return;
  }

  int bin = blockIdx.x;
  int n0 = bin << 9;
  int e0 = baseD[bin];
  int e1 = (bin == NBIN - 1) ? NE : baseD[bin + 1];
  int m = e1 - e0;
  lcnt[t] = 0;
  __syncthreads();
  for (int k = t; k < m; k += 512) atomicAdd(&lcnt[binD[e0 + k].x & 511], 1);
  __syncthreads();
  int myc = lcnt[t];
  bool valid = (n0 + t) < NN;
  if (valid) nd[n0 + t] = rsqrtf(fmaxf((float)myc, 1.f));
  sm[t] = myc; __syncthreads();
  for (int o = 1; o < 512; o <<= 1) {
    int a = (t >= o) ? sm[t - o] : 0;
    __syncthreads();
    sm[t] += a;
    __syncthreads();
  }
  int excl = sm[t] - myc;
  if (valid) offs[n0 + t] = e0 + excl;
  if (bin == NBIN - 1 && t == 0) offs[NN] = NE;
  lcnt[t] = excl;
  __syncthreads();
  for (int k = t; k < m; k += 512) {
    int2 p = binD[e0 + k];
    int q = atomicAdd(&lcnt[p.x & 511], 1);
    if (q < LCSRC) lcsr[q] = p.y; else csr[e0 + q] = p.y;
  }
  __syncthreads();
  int mm = min(m, LCSRC);
  for (int k = t; k < mm; k += 512) csr[e0 + k] = lcsr[k];
}

// ---------------- pull: 3 edges/wave-iter, f16x8 lanes, bpermute edge fetch ----------------
__global__ __launch_bounds__(256) void k_pull(const f16* __restrict__ hh,
    const float* __restrict__ ns, const float* __restrict__ nd,
    const int* __restrict__ offs, const int* __restrict__ csr,
    f16* __restrict__ aggt) {
  int wid = (blockIdx.x * 256 + threadIdx.x) >> 6;
  int lane = threadIdx.x & 63;
  if (wid >= NN) return;
  int lo = offs[wid];
  int deg = min(offs[wid + 1] - lo, 64);

  int sv = 0; float nv = 0.f;
  if (lane < deg) { sv = csr[lo + lane]; nv = ns[sv]; }

  int sub = lane / 19;
  int grp = lane - sub * 19;
  bool act = lane < 57;
  const f16* hcol = hh + grp * 8;

  float acc[8];
#pragma unroll
  for (int k = 0; k < 8; ++k) acc[k] = 0.f;

  for (int g = 0; g < deg; g += 12) {
    int s[4]; float w[4]; f16x8 r[4];
#pragma unroll
    for (int u = 0; u < 4; ++u) {
      int e = g + sub + 3 * u;
      int ec = (e < deg) ? e : 0;
      s[u] = __shfl(sv, ec, 64);
      float ww = __shfl(nv, ec, 64);
      w[u] = (e < deg && act) ? ww : 0.f;
    }
#pragma unroll
    for (int u = 0; u < 4; ++u) r[u] = *(const f16x8*)(hcol + (size_t)s[u] * SP);
#pragma unroll
    for (int u = 0; u < 4; ++u)
#pragma unroll
      for (int k = 0; k < 8; ++k)
        acc[k] = fmaf(w[u], (float)r[u][k], acc[k]);
  }

#pragma unroll
  for (int k = 0; k < 8; ++k) {
    float a1 = __shfl(acc[k], lane + 19, 64);
    float a2 = __shfl(acc[k], lane + 38, 64);
    acc[k] += a1 + a2;
  }

  if (lane < 20) {
    float sc = nd[wid];
    int B = wid >> 4, pos = wid & 15;
    f16x8 o = (f16x8)(f16)0;
    if (lane < 19) {
#pragma unroll
      for (int k = 0; k < 8; ++k) o[k] = (f16)(acc[k] * sc);
    }
    *(f16x8*)(aggt + ((size_t)(B * 20 + lane) * 16 + pos) * 8) = o;
  }
}

// ---------------- layer MFMA GEMM: h2 = (agg @ W + b) * snorm; BN sums -> stsum (atomic) --
__global__ __launch_bounds__(256) void k_mfma(
    const f16* __restrict__ At, const f16* __restrict__ Wt,
    const float* __restrict__ bp, const float* __restrict__ snorm,
    f16* __restrict__ Ch, float* __restrict__ stsum) {
  __shared__ __align__(16) f16 As[8 * 512];
  __shared__ __align__(16) f16 Ws[10 * 512];
  __shared__ float bsum[160], bsq[160];

  int t = threadIdx.x;
  int w = t >> 6, l = t & 63;
  int wr = w >> 1, wc = w & 1;
  int l15 = l & 15, l4 = l >> 4;
  int RB0 = blockIdx.x * 8;

  if (t < 160) { bsum[t] = 0.f; bsq[t] = 0.f; }

  f32x4 acc[4][5];
#pragma unroll
  for (int i = 0; i < 4; ++i)
#pragma unroll
    for (int j = 0; j < 5; ++j) acc[i][j] = (f32x4)0.f;

#pragma unroll 1
  for (int s = 0; s < 5; ++s) {
    __syncthreads();
#pragma unroll
    for (int u = 0; u < 2; ++u) {
      int i = t + u * 256;
      int rb = i >> 6, p = i & 63;
      int RB = RB0 + rb;
      f16x8 v = (f16x8)(f16)0;
      if (RB < NRB) v = *(const f16x8*)(At + ((size_t)RB * 20 + 4 * s) * 128 + p * 8);
      *(f16x8*)(As + rb * 512 + p * 8) = v;
    }
#pragma unroll
    for (int u = 0; u < 3; ++u) {
      int m = t + u * 256;
      if (m < 640) {
        int cb = m >> 6, p = m & 63;
        f16x8 v = *(const f16x8*)(Wt + ((size_t)cb * 20 + 4 * s) * 128 + p * 8);
        *(f16x8*)(Ws + cb * 512 + p * 8) = v;
      }
    }
    __syncthreads();

    f16x8 af[4], bf[5];
#pragma unroll
    for (int i = 0; i < 4; ++i)
      af[i] = *(const f16x8*)(As + (wr * 4 + i) * 512 + l4 * 128 + l15 * 8);
#pragma unroll
    for (int j = 0; j < 5; ++j)
      bf[j] = *(const f16x8*)(Ws + (wc * 5 + j) * 512 + l4 * 128 + l15 * 8);
#pragma unroll
    for (int i = 0; i < 4; ++i)
#pragma unroll
      for (int j = 0; j < 5; ++j)
        acc[i][j] = __builtin_amdgcn_mfma_f32_16x16x32_f16(af[i], bf[j], acc[i][j], 0, 0, 0);
  }

  float cs[5], cq[5];
#pragma unroll
  for (int j = 0; j < 5; ++j) { cs[j] = 0.f; cq[j] = 0.f; }

  int colbase = wc * 80;
  int rowbase = RB0 * 16 + wr * 64;
#pragma unroll
  for (int i = 0; i < 4; ++i) {
#pragma unroll
    for (int r = 0; r < 4; ++r) {
      int row = rowbase + i * 16 + l4 * 4 + r;
      bool ok = row < NN;
      float sn = ok ? snorm[row] : 1.f;
#pragma unroll
      for (int j = 0; j < 5; ++j) {
        int col = colbase + j * 16 + l15;
        float v = (acc[i][j][r] + bp[col]) * sn;
        if (ok) {
          if (col < SP) Ch[(size_t)row * 160 + col] = (f16)v;
          cs[j] += v;
          cq[j] = fmaf(v, v, cq[j]);
        }
      }
    }
  }
#pragma unroll
  for (int j = 0; j < 5; ++j) {
    int col = colbase + j * 16 + l15;
    atomicAdd(&bsum[col], cs[j]);
    atomicAdd(&bsq[col], cq[j]);
  }
  __syncthreads();
  if (t < 160) {
    atomicAdd(&stsum[t], bsum[t]);
    atomicAdd(&stsum[160 + t], bsq[t]);
  }
}

// ---------------- update (BN finalize fused): hh += relu(h2*a+b2), f16x8 ----------------
__global__ __launch_bounds__(256) void k_update(const f16* __restrict__ h2,
    const float* __restrict__ st, const float* __restrict__ g,
    const float* __restrict__ bt, f16* __restrict__ hh) {
  __shared__ float ab[320];
  int t = threadIdx.x;
  if (t < 160) {
    float m = st[t] * (1.f / NN);
    float q = st[160 + t] * (1.f / NN);
    float iv = rsqrtf(q - m * m + EPSF);
    float gg = (t < HD) ? g[t] : 0.f;
    float bb = (t < HD) ? bt[t] : 0.f;
    float a = iv * gg;
    ab[t] = a;
    ab[160 + t] = bb - m * a;
  }
  __syncthreads();
  int idx = blockIdx.x * 256 + t;
  if (idx >= NN * 19) return;
  int r = idx / 19, gq = idx - r * 19;
  int c = gq * 8;
  f16x8 p = *(const f16x8*)(h2 + (size_t)r * 160 + c);
  f16x8 hv = *(const f16x8*)(hh + (size_t)r * SP + c);
  f16x8 ho;
#pragma unroll
  for (int j = 0; j < 8; ++j) {
    float v = fmaf((float)p[j], ab[c + j], ab[160 + c + j]);
    float hn = (float)hv[j] + fmaxf(v, 0.f);
    ho[j] = (f16)hn;
  }
  *(f16x8*)(hh + (size_t)r * SP + c) = ho;
}

// ---------------- fused layer-3 update + readout + last-block divide ----------------
__global__ __launch_bounds__(256) void k_rdfuse(const f16* __restrict__ h2,
    const f16* __restrict__ hh, const float* __restrict__ st,
    const float* __restrict__ g, const float* __restrict__ bt,
    const int* __restrict__ gb, float* __restrict__ out16,
    int* __restrict__ rcnt, float* __restrict__ out) {
  __shared__ float sa[148], sb[148], sacc[148];
  __shared__ int lastflag;
  int t = threadIdx.x;
  if (t < 148) {
    float m = st[t] * (1.f / NN);
    float q = st[160 + t] * (1.f / NN);
    float iv = rsqrtf(q - m * m + EPSF);
    float gg = (t < HD) ? g[t] : 0.f;
    float bb = (t < HD) ? bt[t] : 0.f;
    float a = iv * gg;
    sa[t] = a;
    sb[t] = bb - m * a;
    sacc[t] = 0.f;
  }
  __syncthreads();
  int gr = blockIdx.x >> 4, chunk = blockIdx.x & 15;
  int lo = gb[gr], hi = gb[gr + 1];
  int w = t >> 6, lane = t & 63;
  f32x4 acc = (f32x4)0.f;
  if (lane < 37) {
    int c = lane * 4;
    for (int r = lo + chunk * 4 + w; r < hi; r += 64) {
      f16x4 p = *(const f16x4*)(h2 + (size_t)r * 160 + c);
      f16x4 hv = *(const f16x4*)(hh + (size_t)r * SP + c);
#pragma unroll
      for (int j = 0; j < 4; ++j) {
        float v = fmaf((float)p[j], sa[c + j], sb[c + j]);
        acc[j] += (float)hv[j] + fmaxf(v, 0.f);
      }
    }
    atomicAdd(&sacc[c + 0], acc[0]);
    atomicAdd(&sacc[c + 1], acc[1]);
    atomicAdd(&sacc[c + 2], acc[2]);
    atomicAdd(&sacc[c + 3], acc[3]);
  }
  __syncthreads();
  if (t < 148)
    out16[((size_t)chunk * NG + gr) * 148 + t] = sacc[t];
  __syncthreads();
  if (t == 0) {
    __threadfence();
    lastflag = (atomicAdd(&rcnt[gr], 1) == 15);
  }
  __syncthreads();
  if (lastflag && t < HD) {
    float s = 0.f;
#pragma unroll
    for (int ch = 0; ch < 16; ++ch) s += out16[((size_t)ch * NG + gr) * 148 + t];
    out[gr * HD + t] = s / fmaxf((float)(hi - lo), 1.f);
  }
}

extern "C" void kernel_launch(void* const* d_in, const int* in_sizes, int n_in,
                              void* d_out, int out_size, void* d_ws, size_t ws_size,
                              hipStream_t stream) {
  const float* X     = (const float*)d_in[0];
  const float* snorm = (const float*)d_in[1];
  const float* W_e   = (const float*)d_in[2];
  const float* b_e   = (const float*)d_in[3];
  const float* Wl[3]  = {(const float*)d_in[4], (const float*)d_in[8],  (const float*)d_in[12]};
  const float* bl[3]  = {(const float*)d_in[5], (const float*)d_in[9],  (const float*)d_in[13]};
  const float* gl[3]  = {(const float*)d_in[6], (const float*)d_in[10], (const float*)d_in[14]};
  const float* btl[3] = {(const float*)d_in[7], (const float*)d_in[11], (const float*)d_in[15]};
  const int* src = (const int*)d_in[16];
  const int* dst = (const int*)d_in[17];
  const int* gid = (const int*)d_in[18];
  float* out = (float*)d_out;

  char* p = (char*)d_ws;
  f16* hh    = (f16*)p;   p += sizeof(f16) * (size_t)NN * SP;          // 30.4 MB
  f16* aggt  = (f16*)p;   p += sizeof(f16) * (size_t)NRB * 20 * 128;   // 32 MB (h2, binD/S alias)
  f16* WtE   = (f16*)p;   p += sizeof(f16) * 10240;
  f16* Wt    = (f16*)p;   p += sizeof(f16) * 3 * 25600;
  float* bp  = (float*)p; p += sizeof(float) * 4 * 160;
  float* out16 = (float*)p; p += sizeof(float) * 16 * NG * 148;        // 2.42 MB
  float* stsum3 = (float*)p; p += sizeof(float) * 960;
  float* ns  = (float*)p; p += sizeof(float) * NN;
  float* nd  = (float*)p; p += sizeof(float) * NN;
  int* offs = (int*)p; p += sizeof(int) * (NN + 1);
  int* csr  = (int*)p; p += sizeof(int) * NE;                          // 4 MB
  int* bhD  = (int*)p; p += sizeof(int) * NBIN * NCH;                  // 383 KB
  int* bhS  = (int*)p; p += sizeof(int) * NBIN * NCH;
  int* btotD = (int*)p; p += sizeof(int) * NBIN;
  int* btotS = (int*)p; p += sizeof(int) * NBIN;
  int* baseD = (int*)p; p += sizeof(int) * NBIN;
  int* baseS = (int*)p; p += sizeof(int) * NBIN;
  int* gb   = (int*)p; p += sizeof(int) * (NG + 1);
  int* rcnt = (int*)p; p += sizeof(int) * NG;

  int2* binD = (int2*)aggt;
  int*  binS = (int*)(aggt + (size_t)NE * 4);
  f16* h2 = aggt;

  // ---- build + prep (13 dispatches total) ----
  k_A<<<NCH + PREPB, 256, 0, stream>>>(src, dst, bhD, bhS,
                                       W_e, Wl[0], Wl[1], Wl[2], b_e, bl[0], bl[1], bl[2],
                                       WtE, Wt, bp, gid, gb, stsum3, rcnt);
  k_p2<<<2 * NBIN, 512, 0, stream>>>(bhD, bhS, btotD, btotS);
  k_B<<<NCH + GB, 256, 0, stream>>>(src, dst, bhD, bhS, btotD, btotS,
                                    baseD, baseS, binD, binS, X, WtE, bp, hh);
  k_p56<<<2 * NBIN, 512, 0, stream>>>(binD, baseD, binS, baseS, offs, csr, nd, ns);

  for (int l = 0; l < 3; ++l) {
    k_pull<<<(NN * 64 + 255) / 256, 256, 0, stream>>>(hh, ns, nd, offs, csr, aggt);
    k_mfma<<<GB, 256, 0, stream>>>(aggt, Wt + l * 25600, bp + (l + 1) * 160,
                                   snorm, h2, stsum3 + l * 320);
    if (l < 2) {
      k_update<<<(NN * 19 + 255) / 256, 256, 0, stream>>>(h2, stsum3 + l * 320,
                                                          gl[l], btl[l], hh);
    } else {
      k_rdfuse<<<NG * 16, 256, 0, stream>>>(h2, hh, stsum3 + 640, gl[2], btl[2],
                                            gb, out16, rcnt, out);
    }
  }
}

// Round 18
// 496.945 us; speedup vs baseline: 1.1710x; 1.1710x over previous
//
#include <hip/hip_runtime.h>

#define NN 100000
#define NE 1000000
#define NG 256
#define HD 146
#define SP 152          // padded row stride for hh (f16): 19 x f16x8
#define EPSF 1e-5f
#define NRB 6250        // NN/16 row-blocks (exact)
#define GB 782          // MFMA grid = ceil(NRB/8)

// binned CSR build
#define NBIN 196        // ceil(NN/512)
#define CHUNK 2048
#define NCH 489         // ceil(NE/2048)
#define LCSRC 6144      // per-bin LDS CSR capacity
#define PREPB 349       // prep blocks: ceil(89152/256)

typedef _Float16 f16;
typedef f16 f16x8 __attribute__((ext_vector_type(8)));
typedef f16 f16x4 __attribute__((ext_vector_type(4)));
typedef float f32x4 __attribute__((ext_vector_type(4)));

// ---------------- k_A = p1 histograms (blocks<NCH) + one-shot prep ----------------
__global__ __launch_bounds__(256) void k_A(const int* __restrict__ src,
    const int* __restrict__ dst, int* __restrict__ bhD, int* __restrict__ bhS,
    const float* __restrict__ W_e, const float* __restrict__ W1,
    const float* __restrict__ W2, const float* __restrict__ W3,
    const float* __restrict__ b_e, const float* __restrict__ b1,
    const float* __restrict__ b2, const float* __restrict__ b3,
    f16* __restrict__ WtE, f16* __restrict__ Wt, float* __restrict__ bp,
    const int* __restrict__ gid, int* __restrict__ gb,
    float* __restrict__ stsum3) {
  __shared__ int hd[NBIN], hs[NBIN];
  int t = threadIdx.x;
  if (blockIdx.x < NCH) {
    if (t < NBIN) { hd[t] = 0; hs[t] = 0; }
    __syncthreads();
    int base = blockIdx.x * CHUNK;
#pragma unroll
    for (int i = 0; i < 8; ++i) {
      int e = base + i * 256 + t;
      if (e < NE) {
        atomicAdd(&hd[dst[e] >> 9], 1);
        atomicAdd(&hs[src[e] >> 9], 1);
      }
    }
    __syncthreads();
    if (t < NBIN) {
      bhD[t * NCH + blockIdx.x] = hd[t];
      bhS[t * NCH + blockIdx.x] = hs[t];
    }
    return;
  }
  int idx = (blockIdx.x - NCH) * 256 + t;
  if (idx < 10240) {                       // W_e [64][146] -> [10 cb][8 kg][16][8]
    int j = idx & 7, pos = (idx >> 3) & 15;
    int rem = idx >> 7;
    int kg = rem & 7, cb = rem >> 3;
    int c = cb * 16 + pos, k = kg * 8 + j;
    WtE[idx] = (c < HD) ? (f16)W_e[k * HD + c] : (f16)0;
  } else if (idx < 87040) {                // W_l [146][146] -> [10 cb][20 kg][16][8] x3
    int i2 = idx - 10240;
    int l = i2 / 25600, m = i2 % 25600;
    const float* W = (l == 0) ? W1 : (l == 1) ? W2 : W3;
    int j = m & 7, pos = (m >> 3) & 15;
    int rem = m >> 7;
    int kg = rem % 20, cb = rem / 20;
    int c = cb * 16 + pos, k = kg * 8 + j;
    Wt[i2] = (k < HD && c < HD) ? (f16)W[k * HD + c] : (f16)0;
  } else if (idx < 87680) {                // biases padded to 160, x4
    int i2 = idx - 87040;
    int which = i2 / 160, tt = i2 % 160;
    const float* b = (which == 0) ? b_e : (which == 1) ? b1 : (which == 2) ? b2 : b3;
    bp[i2] = (tt < HD) ? b[tt] : 0.f;
  } else if (idx < 88192) {                // graph row bounds (gid sorted)
    int g = idx - 87680;
    if (g <= NG) {
      int lo = 0, hi = NN;
      while (lo < hi) {
        int m = (lo + hi) >> 1;
        if (gid[m] < g) lo = m + 1; else hi = m;
      }
      gb[g] = lo;
    }
  } else if (idx < 89152) {                // BN stat accumulators, 3 x 320
    stsum3[idx - 88192] = 0.f;
  }
}

// ---------------- pass 2: per-bin exclusive scan over blocks ----------------
__global__ __launch_bounds__(512) void k_p2(int* __restrict__ bhD, int* __restrict__ bhS,
                                            int* __restrict__ btotD, int* __restrict__ btotS) {
  __shared__ int sm[512];
  int B = blockIdx.x % NBIN;
  bool isS = blockIdx.x >= NBIN;
  int* bh = isS ? bhS : bhD;
  int* btot = isS ? btotS : btotD;
  int t = threadIdx.x;
  int v = (t < NCH) ? bh[B * NCH + t] : 0;
  sm[t] = v; __syncthreads();
  for (int o = 1; o < 512; o <<= 1) {
    int a = (t >= o) ? sm[t - o] : 0;
    __syncthreads();
    sm[t] += a;
    __syncthreads();
  }
  if (t < NCH) bh[B * NCH + t] = sm[t] - v;
  if (t == 511) btot[B] = sm[511];
}

// ---------------- k_B = p4 scatter w/ inline base scans (blocks<NCH) + membed ----------
__global__ __launch_bounds__(256) void k_B(const int* __restrict__ src,
    const int* __restrict__ dst, const int* __restrict__ bhD, const int* __restrict__ bhS,
    const int* __restrict__ btotD, const int* __restrict__ btotS,
    int* __restrict__ baseD, int* __restrict__ baseS,
    int2* __restrict__ binD, int* __restrict__ binS,
    const float* __restrict__ X, const f16* __restrict__ WtE,
    const float* __restrict__ bp, f16* __restrict__ Hh) {
  __shared__ int curD[NBIN], curS[NBIN], sm2[256];
  __shared__ __align__(16) f16 As[8 * 512];
  __shared__ __align__(16) f16 Ws[10 * 512];
  int t = threadIdx.x;

  if (blockIdx.x < NCH) {
    int v = (t < NBIN) ? btotD[t] : 0;
    sm2[t] = v; __syncthreads();
    for (int o = 1; o < 256; o <<= 1) {
      int a = (t >= o) ? sm2[t - o] : 0;
      __syncthreads();
      sm2[t] += a;
      __syncthreads();
    }
    int bD = sm2[t] - v;
    if (t < NBIN) {
      curD[t] = bD + bhD[t * NCH + blockIdx.x];
      if (blockIdx.x == 0) baseD[t] = bD;
    }
    __syncthreads();
    v = (t < NBIN) ? btotS[t] : 0;
    sm2[t] = v; __syncthreads();
    for (int o = 1; o < 256; o <<= 1) {
      int a = (t >= o) ? sm2[t - o] : 0;
      __syncthreads();
      sm2[t] += a;
      __syncthreads();
    }
    int bS = sm2[t] - v;
    if (t < NBIN) {
      curS[t] = bS + bhS[t * NCH + blockIdx.x];
      if (blockIdx.x == 0) baseS[t] = bS;
    }
    __syncthreads();
    int base = blockIdx.x * CHUNK;
#pragma unroll
    for (int i = 0; i < 8; ++i) {
      int e = base + i * 256 + t;
      if (e < NE) {
        int d = dst[e], s = src[e];
        int pD = atomicAdd(&curD[d >> 9], 1);
        binD[pD] = make_int2(d, s);
        int pS = atomicAdd(&curS[s >> 9], 1);
        binS[pS] = s;
      }
    }
    return;
  }

  // ---- membed: hh = f16(X) @ WtE + bp ----
  int w = t >> 6, l = t & 63;
  int wr = w >> 1, wc = w & 1;
  int l15 = l & 15, l4 = l >> 4;
  int RB0 = (blockIdx.x - NCH) * 8;

  f32x4 acc[4][5];
#pragma unroll
  for (int i = 0; i < 4; ++i)
#pragma unroll
    for (int j = 0; j < 5; ++j) acc[i][j] = (f32x4)0.f;

#pragma unroll 1
  for (int s = 0; s < 2; ++s) {
    __syncthreads();
#pragma unroll
    for (int u = 0; u < 2; ++u) {
      int i = t + u * 256;
      int rb = i >> 6, p = i & 63;
      int kg = 4 * s + (p >> 4), pos = p & 15;
      int row = (RB0 + rb) * 16 + pos;
      f16x8 v = (f16x8)(f16)0;
      if (row < NN) {
        const float4* xp = (const float4*)(X + (size_t)row * 64 + kg * 8);
        float4 a = xp[0], b = xp[1];
        v[0] = (f16)a.x; v[1] = (f16)a.y; v[2] = (f16)a.z; v[3] = (f16)a.w;
        v[4] = (f16)b.x; v[5] = (f16)b.y; v[6] = (f16)b.z; v[7] = (f16)b.w;
      }
      *(f16x8*)(As + rb * 512 + p * 8) = v;
    }
#pragma unroll
    for (int u = 0; u < 3; ++u) {
      int m = t + u * 256;
      if (m < 640) {
        int cb = m >> 6, p = m & 63;
        f16x8 v = *(const f16x8*)(WtE + ((size_t)cb * 8 + 4 * s) * 128 + p * 8);
        *(f16x8*)(Ws + cb * 512 + p * 8) = v;
      }
    }
    __syncthreads();

    f16x8 af[4], bf[5];
#pragma unroll
    for (int i = 0; i < 4; ++i)
      af[i] = *(const f16x8*)(As + (wr * 4 + i) * 512 + l4 * 128 + l15 * 8);
#pragma unroll
    for (int j = 0; j < 5; ++j)
      bf[j] = *(const f16x8*)(Ws + (wc * 5 + j) * 512 + l4 * 128 + l15 * 8);
#pragma unroll
    for (int i = 0; i < 4; ++i)
#pragma unroll
      for (int j = 0; j < 5; ++j)
        acc[i][j] = __builtin_amdgcn_mfma_f32_16x16x32_f16(af[i], bf[j], acc[i][j], 0, 0, 0);
  }

  int colbase = wc * 80;
  int rowbase = RB0 * 16 + wr * 64;
#pragma unroll
  for (int i = 0; i < 4; ++i) {
#pragma unroll
    for (int r = 0; r < 4; ++r) {
      int row = rowbase + i * 16 + l4 * 4 + r;
      if (row < NN) {
#pragma unroll
        for (int j = 0; j < 5; ++j) {
          int col = colbase + j * 16 + l15;
          float v = acc[i][j][r] + bp[col];
          if (col < HD) Hh[(size_t)row * SP + col] = (f16)v;
          else if (col < SP) Hh[(size_t)row * SP + col] = (f16)0;
        }
      }
    }
  }
}

// ---------------- pass 5+6 merged: per-bin CSR (dst) / out-degree (src) ----------------
__global__ __launch_bounds__(512) void k_p56(const int2* __restrict__ binD,
                                             const int* __restrict__ baseD,
                                             const int* __restrict__ binS,
                                             const int* __restrict__ baseS,
                                             int* __restrict__ offs, int* __restrict__ csr,
                                             float* __restrict__ nd, float* __restrict__ ns) {
  __shared__ int lcnt[512];
  __shared__ int sm[512];
  __shared__ int lcsr[LCSRC];
  int t = threadIdx.x;

  if (blockIdx.x >= NBIN) {
    int bin = blockIdx.x - NBIN;
    int n0 = bin << 9;
    int e0 = baseS[bin];
    int e1 = (bin == NBIN - 1) ? NE : baseS[bin + 1];
    int m = e1 - e0;
    lcnt[t] = 0; __syncthreads();
    for (int k = t; k < m; k += 512) atomicAdd(&lcnt[binS[e0 + k] & 511], 1);
    __syncthreads();
    if (n0 + t < NN) ns[n0 + t] = rsqrtf(fmaxf((float)lcnt[t], 1.f));
    return;
  }

  int bin = blockIdx.x;
  int n0 = bin << 9;
  int e0 = baseD[bin];
  int e1 = (bin == NBIN - 1) ? NE : baseD[bin + 1];
  int m = e1 - e0;
  lcnt[t] = 0;
  __syncthreads();
  for (int k = t; k < m; k += 512) atomicAdd(&lcnt[binD[e0 + k].x & 511], 1);
  __syncthreads();
  int myc = lcnt[t];
  bool valid = (n0 + t) < NN;
  if (valid) nd[n0 + t] = rsqrtf(fmaxf((float)myc, 1.f));
  sm[t] = myc; __syncthreads();
  for (int o = 1; o < 512; o <<= 1) {
    int a = (t >= o) ? sm[t - o] : 0;
    __syncthreads();
    sm[t] += a;
    __syncthreads();
  }
  int excl = sm[t] - myc;
  if (valid) offs[n0 + t] = e0 + excl;
  if (bin == NBIN - 1 && t == 0) offs[NN] = NE;
  lcnt[t] = excl;
  __syncthreads();
  for (int k = t; k < m; k += 512) {
    int2 p = binD[e0 + k];
    int q = atomicAdd(&lcnt[p.x & 511], 1);
    if (q < LCSRC) lcsr[q] = p.y; else csr[e0 + q] = p.y;
  }
  __syncthreads();
  int mm = min(m, LCSRC);
  for (int k = t; k < mm; k += 512) csr[e0 + k] = lcsr[k];
}

// ---------------- pull: 3 edges/wave-iter, f16x8 lanes, bpermute edge fetch ----------------
__global__ __launch_bounds__(256) void k_pull(const f16* __restrict__ hh,
    const float* __restrict__ ns, const float* __restrict__ nd,
    const int* __restrict__ offs, const int* __restrict__ csr,
    f16* __restrict__ aggt) {
  int wid = (blockIdx.x * 256 + threadIdx.x) >> 6;
  int lane = threadIdx.x & 63;
  if (wid >= NN) return;
  int lo = offs[wid];
  int deg = min(offs[wid + 1] - lo, 64);

  int sv = 0; float nv = 0.f;
  if (lane < deg) { sv = csr[lo + lane]; nv = ns[sv]; }

  int sub = lane / 19;
  int grp = lane - sub * 19;
  bool act = lane < 57;
  const f16* hcol = hh + grp * 8;

  float acc[8];
#pragma unroll
  for (int k = 0; k < 8; ++k) acc[k] = 0.f;

  for (int g = 0; g < deg; g += 12) {
    int s[4]; float w[4]; f16x8 r[4];
#pragma unroll
    for (int u = 0; u < 4; ++u) {
      int e = g + sub + 3 * u;
      int ec = (e < deg) ? e : 0;
      s[u] = __shfl(sv, ec, 64);
      float ww = __shfl(nv, ec, 64);
      w[u] = (e < deg && act) ? ww : 0.f;
    }
#pragma unroll
    for (int u = 0; u < 4; ++u) r[u] = *(const f16x8*)(hcol + (size_t)s[u] * SP);
#pragma unroll
    for (int u = 0; u < 4; ++u)
#pragma unroll
      for (int k = 0; k < 8; ++k)
        acc[k] = fmaf(w[u], (float)r[u][k], acc[k]);
  }

#pragma unroll
  for (int k = 0; k < 8; ++k) {
    float a1 = __shfl(acc[k], lane + 19, 64);
    float a2 = __shfl(acc[k], lane + 38, 64);
    acc[k] += a1 + a2;
  }

  if (lane < 20) {
    float sc = nd[wid];
    int B = wid >> 4, pos = wid & 15;
    f16x8 o = (f16x8)(f16)0;
    if (lane < 19) {
#pragma unroll
      for (int k = 0; k < 8; ++k) o[k] = (f16)(acc[k] * sc);
    }
    *(f16x8*)(aggt + ((size_t)(B * 20 + lane) * 16 + pos) * 8) = o;
  }
}

// ---------------- layer MFMA GEMM: h2 = (agg @ W + b) * snorm; BN sums -> stsum (atomic) --
__global__ __launch_bounds__(256) void k_mfma(
    const f16* __restrict__ At, const f16* __restrict__ Wt,
    const float* __restrict__ bp, const float* __restrict__ snorm,
    f16* __restrict__ Ch, float* __restrict__ stsum) {
  __shared__ __align__(16) f16 As[8 * 512];
  __shared__ __align__(16) f16 Ws[10 * 512];
  __shared__ float bsum[160], bsq[160];

  int t = threadIdx.x;
  int w = t >> 6, l = t & 63;
  int wr = w >> 1, wc = w & 1;
  int l15 = l & 15, l4 = l >> 4;
  int RB0 = blockIdx.x * 8;

  if (t < 160) { bsum[t] = 0.f; bsq[t] = 0.f; }

  f32x4 acc[4][5];
#pragma unroll
  for (int i = 0; i < 4; ++i)
#pragma unroll
    for (int j = 0; j < 5; ++j) acc[i][j] = (f32x4)0.f;

#pragma unroll 1
  for (int s = 0; s < 5; ++s) {
    __syncthreads();
#pragma unroll
    for (int u = 0; u < 2; ++u) {
      int i = t + u * 256;
      int rb = i >> 6, p = i & 63;
      int RB = RB0 + rb;
      f16x8 v = (f16x8)(f16)0;
      if (RB < NRB) v = *(const f16x8*)(At + ((size_t)RB * 20 + 4 * s) * 128 + p * 8);
      *(f16x8*)(As + rb * 512 + p * 8) = v;
    }
#pragma unroll
    for (int u = 0; u < 3; ++u) {
      int m = t + u * 256;
      if (m < 640) {
        int cb = m >> 6, p = m & 63;
        f16x8 v = *(const f16x8*)(Wt + ((size_t)cb * 20 + 4 * s) * 128 + p * 8);
        *(f16x8*)(Ws + cb * 512 + p * 8) = v;
      }
    }
    __syncthreads();

    f16x8 af[4], bf[5];
#pragma unroll
    for (int i = 0; i < 4; ++i)
      af[i] = *(const f16x8*)(As + (wr * 4 + i) * 512 + l4 * 128 + l15 * 8);
#pragma unroll
    for (int j = 0; j < 5; ++j)
      bf[j] = *(const f16x8*)(Ws + (wc * 5 + j) * 512 + l4 * 128 + l15 * 8);
#pragma unroll
    for (int i = 0; i < 4; ++i)
#pragma unroll
      for (int j = 0; j < 5; ++j)
        acc[i][j] = __builtin_amdgcn_mfma_f32_16x16x32_f16(af[i], bf[j], acc[i][j], 0, 0, 0);
  }

  float cs[5], cq[5];
#pragma unroll
  for (int j = 0; j < 5; ++j) { cs[j] = 0.f; cq[j] = 0.f; }

  int colbase = wc * 80;
  int rowbase = RB0 * 16 + wr * 64;
#pragma unroll
  for (int i = 0; i < 4; ++i) {
#pragma unroll
    for (int r = 0; r < 4; ++r) {
      int row = rowbase + i * 16 + l4 * 4 + r;
      bool ok = row < NN;
      float sn = ok ? snorm[row] : 1.f;
#pragma unroll
      for (int j = 0; j < 5; ++j) {
        int col = colbase + j * 16 + l15;
        float v = (acc[i][j][r] + bp[col]) * sn;
        if (ok) {
          if (col < SP) Ch[(size_t)row * 160 + col] = (f16)v;
          cs[j] += v;
          cq[j] = fmaf(v, v, cq[j]);
        }
      }
    }
  }
#pragma unroll
  for (int j = 0; j < 5; ++j) {
    int col = colbase + j * 16 + l15;
    atomicAdd(&bsum[col], cs[j]);
    atomicAdd(&bsq[col], cq[j]);
  }
  __syncthreads();
  if (t < 160) {
    atomicAdd(&stsum[t], bsum[t]);
    atomicAdd(&stsum[160 + t], bsq[t]);
  }
}

// ---------------- update (BN finalize fused): hh += relu(h2*a+b2), f16x8 ----------------
__global__ __launch_bounds__(256) void k_update(const f16* __restrict__ h2,
    const float* __restrict__ st, const float* __restrict__ g,
    const float* __restrict__ bt, f16* __restrict__ hh) {
  __shared__ float ab[320];
  int t = threadIdx.x;
  if (t < 160) {
    float m = st[t] * (1.f / NN);
    float q = st[160 + t] * (1.f / NN);
    float iv = rsqrtf(q - m * m + EPSF);
    float gg = (t < HD) ? g[t] : 0.f;
    float bb = (t < HD) ? bt[t] : 0.f;
    float a = iv * gg;
    ab[t] = a;
    ab[160 + t] = bb - m * a;
  }
  __syncthreads();
  int idx = blockIdx.x * 256 + t;
  if (idx >= NN * 19) return;
  int r = idx / 19, gq = idx - r * 19;
  int c = gq * 8;
  f16x8 p = *(const f16x8*)(h2 + (size_t)r * 160 + c);
  f16x8 hv = *(const f16x8*)(hh + (size_t)r * SP + c);
  f16x8 ho;
#pragma unroll
  for (int j = 0; j < 8; ++j) {
    float v = fmaf((float)p[j], ab[c + j], ab[160 + c + j]);
    float hn = (float)hv[j] + fmaxf(v, 0.f);
    ho[j] = (f16)hn;
  }
  *(f16x8*)(hh + (size_t)r * SP + c) = ho;
}

// ---------------- fused layer-3 update + readout partials (no fence) ----------------
__global__ __launch_bounds__(256) void k_rdfuse(const f16* __restrict__ h2,
    const f16* __restrict__ hh, const float* __restrict__ st,
    const float* __restrict__ g, const float* __restrict__ bt,
    const int* __restrict__ gb, float* __restrict__ out16) {
  __shared__ float sa[148], sb[148], sacc[148];
  int t = threadIdx.x;
  if (t < 148) {
    float m = st[t] * (1.f / NN);
    float q = st[160 + t] * (1.f / NN);
    float iv = rsqrtf(q - m * m + EPSF);
    float gg = (t < HD) ? g[t] : 0.f;
    float bb = (t < HD) ? bt[t] : 0.f;
    float a = iv * gg;
    sa[t] = a;
    sb[t] = bb - m * a;
    sacc[t] = 0.f;
  }
  __syncthreads();
  int gr = blockIdx.x >> 4, chunk = blockIdx.x & 15;
  int lo = gb[gr], hi = gb[gr + 1];
  int w = t >> 6, lane = t & 63;
  f32x4 acc = (f32x4)0.f;
  if (lane < 37) {
    int c = lane * 4;
    for (int r = lo + chunk * 4 + w; r < hi; r += 64) {
      f16x4 p = *(const f16x4*)(h2 + (size_t)r * 160 + c);
      f16x4 hv = *(const f16x4*)(hh + (size_t)r * SP + c);
#pragma unroll
      for (int j = 0; j < 4; ++j) {
        float v = fmaf((float)p[j], sa[c + j], sb[c + j]);
        acc[j] += (float)hv[j] + fmaxf(v, 0.f);
      }
    }
    atomicAdd(&sacc[c + 0], acc[0]);
    atomicAdd(&sacc[c + 1], acc[1]);
    atomicAdd(&sacc[c + 2], acc[2]);
    atomicAdd(&sacc[c + 3], acc[3]);
  }
  __syncthreads();
  if (t < 148)
    out16[((size_t)chunk * NG + gr) * 148 + t] = sacc[t];
}

__global__ void k_rdiv(const int* __restrict__ gb, const float* __restrict__ out16,
                       float* __restrict__ out) {
  int g = blockIdx.x, c = threadIdx.x;
  if (c < HD) {
    float s = 0.f;
#pragma unroll
    for (int ch = 0; ch < 16; ++ch) s += out16[((size_t)ch * NG + g) * 148 + c];
    out[g * HD + c] = s / fmaxf((float)(gb[g + 1] - gb[g]), 1.f);
  }
}

extern "C" void kernel_launch(void* const* d_in, const int* in_sizes, int n_in,
                              void* d_out, int out_size, void* d_ws, size_t ws_size,
                              hipStream_t stream) {
  const float* X     = (const float*)d_in[0];
  const float* snorm = (const float*)d_in[1];
  const float* W_e   = (const float*)d_in[2];
  const float* b_e   = (const float*)d_in[3];
  const float* Wl[3]  = {(const float*)d_in[4], (const float*)d_in[8],  (const float*)d_in[12]};
  const float* bl[3]  = {(const float*)d_in[5], (const float*)d_in[9],  (const float*)d_in[13]};
  const float* gl[3]  = {(const float*)d_in[6], (const float*)d_in[10], (const float*)d_in[14]};
  const float* btl[3] = {(const float*)d_in[7], (const float*)d_in[11], (const float*)d_in[15]};
  const int* src = (const int*)d_in[16];
  const int* dst = (const int*)d_in[17];
  const int* gid = (const int*)d_in[18];
  float* out = (float*)d_out;

  char* p = (char*)d_ws;
  f16* hh    = (f16*)p;   p += sizeof(f16) * (size_t)NN * SP;          // 30.4 MB
  f16* aggt  = (f16*)p;   p += sizeof(f16) * (size_t)NRB * 20 * 128;   // 32 MB (h2, binD/S alias)
  f16* WtE   = (f16*)p;   p += sizeof(f16) * 10240;
  f16* Wt    = (f16*)p;   p += sizeof(f16) * 3 * 25600;
  float* bp  = (float*)p; p += sizeof(float) * 4 * 160;
  float* out16 = (float*)p; p += sizeof(float) * 16 * NG * 148;        // 2.42 MB
  float* stsum3 = (float*)p; p += sizeof(float) * 960;
  float* ns  = (float*)p; p += sizeof(float) * NN;
  float* nd  = (float*)p; p += sizeof(float) * NN;
  int* offs = (int*)p; p += sizeof(int) * (NN + 1);
  int* csr  = (int*)p; p += sizeof(int) * NE;                          // 4 MB
  int* bhD  = (int*)p; p += sizeof(int) * NBIN * NCH;                  // 383 KB
  int* bhS  = (int*)p; p += sizeof(int) * NBIN * NCH;
  int* btotD = (int*)p; p += sizeof(int) * NBIN;
  int* btotS = (int*)p; p += sizeof(int) * NBIN;
  int* baseD = (int*)p; p += sizeof(int) * NBIN;
  int* baseS = (int*)p; p += sizeof(int) * NBIN;
  int* gb   = (int*)p; p += sizeof(int) * (NG + 1);

  int2* binD = (int2*)aggt;
  int*  binS = (int*)(aggt + (size_t)NE * 4);
  f16* h2 = aggt;

  k_A<<<NCH + PREPB, 256, 0, stream>>>(src, dst, bhD, bhS,
                                       W_e, Wl[0], Wl[1], Wl[2], b_e, bl[0], bl[1], bl[2],
                                       WtE, Wt, bp, gid, gb, stsum3);
  k_p2<<<2 * NBIN, 512, 0, stream>>>(bhD, bhS, btotD, btotS);
  k_B<<<NCH + GB, 256, 0, stream>>>(src, dst, bhD, bhS, btotD, btotS,
                                    baseD, baseS, binD, binS, X, WtE, bp, hh);
  k_p56<<<2 * NBIN, 512, 0, stream>>>(binD, baseD, binS, baseS, offs, csr, nd, ns);

  for (int l = 0; l < 3; ++l) {
    k_pull<<<(NN * 64 + 255) / 256, 256, 0, stream>>>(hh, ns, nd, offs, csr, aggt);
    k_mfma<<<GB, 256, 0, stream>>>(aggt, Wt + l * 25600, bp + (l + 1) * 160,
                                   snorm, h2, stsum3 + l * 320);
    if (l < 2) {
      k_update<<<(NN * 19 + 255) / 256, 256, 0, stream>>>(h2, stsum3 + l * 320,
                                                          gl[l], btl[l], hh);
    } else {
      k_rdfuse<<<NG * 16, 256, 0, stream>>>(h2, hh, stsum3 + 640, gl[2], btl[2],
                                            gb, out16);
    }
  }
  k_rdiv<<<NG, 192, 0, stream>>>(gb, out16, out);
}

// Round 19
// 478.494 us; speedup vs baseline: 1.2162x; 1.0386x over previous
//
#include <hip/hip_runtime.h>

#define NN 100000
#define NE 1000000
#define NG 256
#define HD 146
#define SP 152          // padded row stride for hh (f16): 19 x f16x8
#define EPSF 1e-5f
#define NRB 6250        // NN/16 row-blocks (exact)
#define GB 782          // MFMA grid = ceil(NRB/8)

// binned CSR build
#define NBIN 196        // ceil(NN/512)
#define CHUNK 2048
#define NCH 489         // ceil(NE/2048)
#define LCSRC 6144      // per-bin LDS CSR capacity
#define PREPB 349       // prep blocks: ceil(89152/256)

typedef _Float16 f16;
typedef f16 f16x8 __attribute__((ext_vector_type(8)));
typedef f16 f16x4 __attribute__((ext_vector_type(4)));
typedef float f32x4 __attribute__((ext_vector_type(4)));

// ---------------- k_A = p1 histograms (blocks<NCH) + one-shot prep ----------------
__global__ __launch_bounds__(256) void k_A(const int* __restrict__ src,
    const int* __restrict__ dst, int* __restrict__ bhD, int* __restrict__ bhS,
    const float* __restrict__ W_e, const float* __restrict__ W1,
    const float* __restrict__ W2, const float* __restrict__ W3,
    const float* __restrict__ b_e, const float* __restrict__ b1,
    const float* __restrict__ b2, const float* __restrict__ b3,
    f16* __restrict__ WtE, f16* __restrict__ Wt, float* __restrict__ bp,
    const int* __restrict__ gid, int* __restrict__ gb) {
  __shared__ int hd[NBIN], hs[NBIN];
  int t = threadIdx.x;
  if (blockIdx.x < NCH) {
    if (t < NBIN) { hd[t] = 0; hs[t] = 0; }
    __syncthreads();
    int base = blockIdx.x * CHUNK;
#pragma unroll
    for (int i = 0; i < 8; ++i) {
      int e = base + i * 256 + t;
      if (e < NE) {
        atomicAdd(&hd[dst[e] >> 9], 1);
        atomicAdd(&hs[src[e] >> 9], 1);
      }
    }
    __syncthreads();
    if (t < NBIN) {
      bhD[t * NCH + blockIdx.x] = hd[t];
      bhS[t * NCH + blockIdx.x] = hs[t];
    }
    return;
  }
  int idx = (blockIdx.x - NCH) * 256 + t;
  if (idx < 10240) {                       // W_e [64][146] -> [10 cb][8 kg][16][8]
    int j = idx & 7, pos = (idx >> 3) & 15;
    int rem = idx >> 7;
    int kg = rem & 7, cb = rem >> 3;
    int c = cb * 16 + pos, k = kg * 8 + j;
    WtE[idx] = (c < HD) ? (f16)W_e[k * HD + c] : (f16)0;
  } else if (idx < 87040) {                // W_l [146][146] -> [10 cb][20 kg][16][8] x3
    int i2 = idx - 10240;
    int l = i2 / 25600, m = i2 % 25600;
    const float* W = (l == 0) ? W1 : (l == 1) ? W2 : W3;
    int j = m & 7, pos = (m >> 3) & 15;
    int rem = m >> 7;
    int kg = rem % 20, cb = rem / 20;
    int c = cb * 16 + pos, k = kg * 8 + j;
    Wt[i2] = (k < HD && c < HD) ? (f16)W[k * HD + c] : (f16)0;
  } else if (idx < 87680) {                // biases padded to 160, x4
    int i2 = idx - 87040;
    int which = i2 / 160, tt = i2 % 160;
    const float* b = (which == 0) ? b_e : (which == 1) ? b1 : (which == 2) ? b2 : b3;
    bp[i2] = (tt < HD) ? b[tt] : 0.f;
  } else if (idx < 88192) {                // graph row bounds (gid sorted)
    int g = idx - 87680;
    if (g <= NG) {
      int lo = 0, hi = NN;
      while (lo < hi) {
        int m = (lo + hi) >> 1;
        if (gid[m] < g) lo = m + 1; else hi = m;
      }
      gb[g] = lo;
    }
  }
}

// ---------------- pass 2: per-bin exclusive scan over blocks ----------------
__global__ __launch_bounds__(512) void k_p2(int* __restrict__ bhD, int* __restrict__ bhS,
                                            int* __restrict__ btotD, int* __restrict__ btotS) {
  __shared__ int sm[512];
  int B = blockIdx.x % NBIN;
  bool isS = blockIdx.x >= NBIN;
  int* bh = isS ? bhS : bhD;
  int* btot = isS ? btotS : btotD;
  int t = threadIdx.x;
  int v = (t < NCH) ? bh[B * NCH + t] : 0;
  sm[t] = v; __syncthreads();
  for (int o = 1; o < 512; o <<= 1) {
    int a = (t >= o) ? sm[t - o] : 0;
    __syncthreads();
    sm[t] += a;
    __syncthreads();
  }
  if (t < NCH) bh[B * NCH + t] = sm[t] - v;
  if (t == 511) btot[B] = sm[511];
}

// ---------------- k_B = p4 scatter w/ inline base scans (blocks<NCH) + membed ----------
__global__ __launch_bounds__(256) void k_B(const int* __restrict__ src,
    const int* __restrict__ dst, const int* __restrict__ bhD, const int* __restrict__ bhS,
    const int* __restrict__ btotD, const int* __restrict__ btotS,
    int* __restrict__ baseD, int* __restrict__ baseS,
    int2* __restrict__ binD, int* __restrict__ binS,
    const float* __restrict__ X, const f16* __restrict__ WtE,
    const float* __restrict__ bp, f16* __restrict__ Hh) {
  __shared__ int curD[NBIN], curS[NBIN], sm2[256];
  __shared__ __align__(16) f16 As[8 * 512];
  __shared__ __align__(16) f16 Ws[10 * 512];
  int t = threadIdx.x;

  if (blockIdx.x < NCH) {
    int v = (t < NBIN) ? btotD[t] : 0;
    sm2[t] = v; __syncthreads();
    for (int o = 1; o < 256; o <<= 1) {
      int a = (t >= o) ? sm2[t - o] : 0;
      __syncthreads();
      sm2[t] += a;
      __syncthreads();
    }
    int bD = sm2[t] - v;
    if (t < NBIN) {
      curD[t] = bD + bhD[t * NCH + blockIdx.x];
      if (blockIdx.x == 0) baseD[t] = bD;
    }
    __syncthreads();
    v = (t < NBIN) ? btotS[t] : 0;
    sm2[t] = v; __syncthreads();
    for (int o = 1; o < 256; o <<= 1) {
      int a = (t >= o) ? sm2[t - o] : 0;
      __syncthreads();
      sm2[t] += a;
      __syncthreads();
    }
    int bS = sm2[t] - v;
    if (t < NBIN) {
      curS[t] = bS + bhS[t * NCH + blockIdx.x];
      if (blockIdx.x == 0) baseS[t] = bS;
    }
    __syncthreads();
    int base = blockIdx.x * CHUNK;
#pragma unroll
    for (int i = 0; i < 8; ++i) {
      int e = base + i * 256 + t;
      if (e < NE) {
        int d = dst[e], s = src[e];
        int pD = atomicAdd(&curD[d >> 9], 1);
        binD[pD] = make_int2(d, s);
        int pS = atomicAdd(&curS[s >> 9], 1);
        binS[pS] = s;
      }
    }
    return;
  }

  // ---- membed: hh = f16(X) @ WtE + bp ----
  int w = t >> 6, l = t & 63;
  int wr = w >> 1, wc = w & 1;
  int l15 = l & 15, l4 = l >> 4;
  int RB0 = (blockIdx.x - NCH) * 8;

  f32x4 acc[4][5];
#pragma unroll
  for (int i = 0; i < 4; ++i)
#pragma unroll
    for (int j = 0; j < 5; ++j) acc[i][j] = (f32x4)0.f;

#pragma unroll 1
  for (int s = 0; s < 2; ++s) {
    __syncthreads();
#pragma unroll
    for (int u = 0; u < 2; ++u) {
      int i = t + u * 256;
      int rb = i >> 6, p = i & 63;
      int kg = 4 * s + (p >> 4), pos = p & 15;
      int row = (RB0 + rb) * 16 + pos;
      f16x8 v = (f16x8)(f16)0;
      if (row < NN) {
        const float4* xp = (const float4*)(X + (size_t)row * 64 + kg * 8);
        float4 a = xp[0], b = xp[1];
        v[0] = (f16)a.x; v[1] = (f16)a.y; v[2] = (f16)a.z; v[3] = (f16)a.w;
        v[4] = (f16)b.x; v[5] = (f16)b.y; v[6] = (f16)b.z; v[7] = (f16)b.w;
      }
      *(f16x8*)(As + rb * 512 + p * 8) = v;
    }
#pragma unroll
    for (int u = 0; u < 3; ++u) {
      int m = t + u * 256;
      if (m < 640) {
        int cb = m >> 6, p = m & 63;
        f16x8 v = *(const f16x8*)(WtE + ((size_t)cb * 8 + 4 * s) * 128 + p * 8);
        *(f16x8*)(Ws + cb * 512 + p * 8) = v;
      }
    }
    __syncthreads();

    f16x8 af[4], bf[5];
#pragma unroll
    for (int i = 0; i < 4; ++i)
      af[i] = *(const f16x8*)(As + (wr * 4 + i) * 512 + l4 * 128 + l15 * 8);
#pragma unroll
    for (int j = 0; j < 5; ++j)
      bf[j] = *(const f16x8*)(Ws + (wc * 5 + j) * 512 + l4 * 128 + l15 * 8);
#pragma unroll
    for (int i = 0; i < 4; ++i)
#pragma unroll
      for (int j = 0; j < 5; ++j)
        acc[i][j] = __builtin_amdgcn_mfma_f32_16x16x32_f16(af[i], bf[j], acc[i][j], 0, 0, 0);
  }

  int colbase = wc * 80;
  int rowbase = RB0 * 16 + wr * 64;
#pragma unroll
  for (int i = 0; i < 4; ++i) {
#pragma unroll
    for (int r = 0; r < 4; ++r) {
      int row = rowbase + i * 16 + l4 * 4 + r;
      if (row < NN) {
#pragma unroll
        for (int j = 0; j < 5; ++j) {
          int col = colbase + j * 16 + l15;
          float v = acc[i][j][r] + bp[col];
          if (col < HD) Hh[(size_t)row * SP + col] = (f16)v;
          else if (col < SP) Hh[(size_t)row * SP + col] = (f16)0;
        }
      }
    }
  }
}

// ---------------- pass 5+6 merged: per-bin CSR (dst) / out-degree (src) ----------------
__global__ __launch_bounds__(512) void k_p56(const int2* __restrict__ binD,
                                             const int* __restrict__ baseD,
                                             const int* __restrict__ binS,
                                             const int* __restrict__ baseS,
                                             int* __restrict__ offs, int* __restrict__ csr,
                                             float* __restrict__ nd, float* __restrict__ ns) {
  __shared__ int lcnt[512];
  __shared__ int sm[512];
  __shared__ int lcsr[LCSRC];
  int t = threadIdx.x;

  if (blockIdx.x >= NBIN) {
    int bin = blockIdx.x - NBIN;
    int n0 = bin << 9;
    int e0 = baseS[bin];
    int e1 = (bin == NBIN - 1) ? NE : baseS[bin + 1];
    int m = e1 - e0;
    lcnt[t] = 0; __syncthreads();
    for (int k = t; k < m; k += 512) atomicAdd(&lcnt[binS[e0 + k] & 511], 1);
    __syncthreads();
    if (n0 + t < NN) ns[n0 + t] = rsqrtf(fmaxf((float)lcnt[t], 1.f));
    return;
  }

  int bin = blockIdx.x;
  int n0 = bin << 9;
  int e0 = baseD[bin];
  int e1 = (bin == NBIN - 1) ? NE : baseD[bin + 1];
  int m = e1 - e0;
  lcnt[t] = 0;
  __syncthreads();
  for (int k = t; k < m; k += 512) atomicAdd(&lcnt[binD[e0 + k].x & 511], 1);
  __syncthreads();
  int myc = lcnt[t];
  bool valid = (n0 + t) < NN;
  if (valid) nd[n0 + t] = rsqrtf(fmaxf((float)myc, 1.f));
  sm[t] = myc; __syncthreads();
  for (int o = 1; o < 512; o <<= 1) {
    int a = (t >= o) ? sm[t - o] : 0;
    __syncthreads();
    sm[t] += a;
    __syncthreads();
  }
  int excl = sm[t] - myc;
  if (valid) offs[n0 + t] = e0 + excl;
  if (bin == NBIN - 1 && t == 0) offs[NN] = NE;
  lcnt[t] = excl;
  __syncthreads();
  for (int k = t; k < m; k += 512) {
    int2 p = binD[e0 + k];
    int q = atomicAdd(&lcnt[p.x & 511], 1);
    if (q < LCSRC) lcsr[q] = p.y; else csr[e0 + q] = p.y;
  }
  __syncthreads();
  int mm = min(m, LCSRC);
  for (int k = t; k < mm; k += 512) csr[e0 + k] = lcsr[k];
}

// ---------------- pull: 3 edges/wave-iter, f16x8 lanes, bpermute edge fetch ----------------
__global__ __launch_bounds__(256) void k_pull(const f16* __restrict__ hh,
    const float* __restrict__ ns, const float* __restrict__ nd,
    const int* __restrict__ offs, const int* __restrict__ csr,
    f16* __restrict__ aggt) {
  int wid = (blockIdx.x * 256 + threadIdx.x) >> 6;
  int lane = threadIdx.x & 63;
  if (wid >= NN) return;
  int lo = offs[wid];
  int deg = min(offs[wid + 1] - lo, 64);

  int sv = 0; float nv = 0.f;
  if (lane < deg) { sv = csr[lo + lane]; nv = ns[sv]; }

  int sub = lane / 19;
  int grp = lane - sub * 19;
  bool act = lane < 57;
  const f16* hcol = hh + grp * 8;

  float acc[8];
#pragma unroll
  for (int k = 0; k < 8; ++k) acc[k] = 0.f;

  for (int g = 0; g < deg; g += 12) {
    int s[4]; float w[4]; f16x8 r[4];
#pragma unroll
    for (int u = 0; u < 4; ++u) {
      int e = g + sub + 3 * u;
      int ec = (e < deg) ? e : 0;
      s[u] = __shfl(sv, ec, 64);
      float ww = __shfl(nv, ec, 64);
      w[u] = (e < deg && act) ? ww : 0.f;
    }
#pragma unroll
    for (int u = 0; u < 4; ++u) r[u] = *(const f16x8*)(hcol + (size_t)s[u] * SP);
#pragma unroll
    for (int u = 0; u < 4; ++u)
#pragma unroll
      for (int k = 0; k < 8; ++k)
        acc[k] = fmaf(w[u], (float)r[u][k], acc[k]);
  }

#pragma unroll
  for (int k = 0; k < 8; ++k) {
    float a1 = __shfl(acc[k], lane + 19, 64);
    float a2 = __shfl(acc[k], lane + 38, 64);
    acc[k] += a1 + a2;
  }

  if (lane < 20) {
    float sc = nd[wid];
    int B = wid >> 4, pos = wid & 15;
    f16x8 o = (f16x8)(f16)0;
    if (lane < 19) {
#pragma unroll
      for (int k = 0; k < 8; ++k) o[k] = (f16)(acc[k] * sc);
    }
    *(f16x8*)(aggt + ((size_t)(B * 20 + lane) * 16 + pos) * 8) = o;
  }
}

// ---------------- layer MFMA GEMM: h2 = (agg @ W + b) * snorm; BN partials -> stp --------
__global__ __launch_bounds__(256) void k_mfma(
    const f16* __restrict__ At, const f16* __restrict__ Wt,
    const float* __restrict__ bp, const float* __restrict__ snorm,
    f16* __restrict__ Ch, float* __restrict__ stp) {
  __shared__ __align__(16) f16 As[8 * 512];
  __shared__ __align__(16) f16 Ws[10 * 512];
  __shared__ float bsum[160], bsq[160];

  int t = threadIdx.x;
  int w = t >> 6, l = t & 63;
  int wr = w >> 1, wc = w & 1;
  int l15 = l & 15, l4 = l >> 4;
  int RB0 = blockIdx.x * 8;

  if (t < 160) { bsum[t] = 0.f; bsq[t] = 0.f; }

  f32x4 acc[4][5];
#pragma unroll
  for (int i = 0; i < 4; ++i)
#pragma unroll
    for (int j = 0; j < 5; ++j) acc[i][j] = (f32x4)0.f;

#pragma unroll 1
  for (int s = 0; s < 5; ++s) {
    __syncthreads();
#pragma unroll
    for (int u = 0; u < 2; ++u) {
      int i = t + u * 256;
      int rb = i >> 6, p = i & 63;
      int RB = RB0 + rb;
      f16x8 v = (f16x8)(f16)0;
      if (RB < NRB) v = *(const f16x8*)(At + ((size_t)RB * 20 + 4 * s) * 128 + p * 8);
      *(f16x8*)(As + rb * 512 + p * 8) = v;
    }
#pragma unroll
    for (int u = 0; u < 3; ++u) {
      int m = t + u * 256;
      if (m < 640) {
        int cb = m >> 6, p = m & 63;
        f16x8 v = *(const f16x8*)(Wt + ((size_t)cb * 20 + 4 * s) * 128 + p * 8);
        *(f16x8*)(Ws + cb * 512 + p * 8) = v;
      }
    }
    __syncthreads();

    f16x8 af[4], bf[5];
#pragma unroll
    for (int i = 0; i < 4; ++i)
      af[i] = *(const f16x8*)(As + (wr * 4 + i) * 512 + l4 * 128 + l15 * 8);
#pragma unroll
    for (int j = 0; j < 5; ++j)
      bf[j] = *(const f16x8*)(Ws + (wc * 5 + j) * 512 + l4 * 128 + l15 * 8);
#pragma unroll
    for (int i = 0; i < 4; ++i)
#pragma unroll
      for (int j = 0; j < 5; ++j)
        acc[i][j] = __builtin_amdgcn_mfma_f32_16x16x32_f16(af[i], bf[j], acc[i][j], 0, 0, 0);
  }

  float cs[5], cq[5];
#pragma unroll
  for (int j = 0; j < 5; ++j) { cs[j] = 0.f; cq[j] = 0.f; }

  int colbase = wc * 80;
  int rowbase = RB0 * 16 + wr * 64;
#pragma unroll
  for (int i = 0; i < 4; ++i) {
#pragma unroll
    for (int r = 0; r < 4; ++r) {
      int row = rowbase + i * 16 + l4 * 4 + r;
      bool ok = row < NN;
      float sn = ok ? snorm[row] : 1.f;
#pragma unroll
      for (int j = 0; j < 5; ++j) {
        int col = colbase + j * 16 + l15;
        float v = (acc[i][j][r] + bp[col]) * sn;
        if (ok) {
          if (col < SP) Ch[(size_t)row * 160 + col] = (f16)v;
          cs[j] += v;
          cq[j] = fmaf(v, v, cq[j]);
        }
      }
    }
  }
#pragma unroll
  for (int j = 0; j < 5; ++j) {
    int col = colbase + j * 16 + l15;
    atomicAdd(&bsum[col], cs[j]);
    atomicAdd(&bsq[col], cq[j]);
  }
  __syncthreads();
  if (t < 160) {
    stp[(size_t)blockIdx.x * 320 + t] = bsum[t];
    stp[(size_t)blockIdx.x * 320 + 160 + t] = bsq[t];
  }
}

// reduce stp[GB][320] -> stsum[320]
__global__ void k_stred(const float* __restrict__ stp, float* __restrict__ stsum) {
  int c = blockIdx.x;
  int t = threadIdx.x;
  float s = 0.f;
  for (int i = t; i < GB; i += 128) s += stp[(size_t)i * 320 + c];
  __shared__ float sm[128];
  sm[t] = s; __syncthreads();
  for (int o = 64; o > 0; o >>= 1) {
    if (t < o) sm[t] += sm[t + o];
    __syncthreads();
  }
  if (t == 0) stsum[c] = sm[0];
}

// ---------------- update (BN finalize fused): hh += relu(h2*a+b2), f16x8 ----------------
__global__ __launch_bounds__(256) void k_update(const f16* __restrict__ h2,
    const float* __restrict__ st, const float* __restrict__ g,
    const float* __restrict__ bt, f16* __restrict__ hh) {
  __shared__ float ab[320];
  int t = threadIdx.x;
  if (t < 160) {
    float m = st[t] * (1.f / NN);
    float q = st[160 + t] * (1.f / NN);
    float iv = rsqrtf(q - m * m + EPSF);
    float gg = (t < HD) ? g[t] : 0.f;
    float bb = (t < HD) ? bt[t] : 0.f;
    float a = iv * gg;
    ab[t] = a;
    ab[160 + t] = bb - m * a;
  }
  __syncthreads();
  int idx = blockIdx.x * 256 + t;
  if (idx >= NN * 19) return;
  int r = idx / 19, gq = idx - r * 19;
  int c = gq * 8;
  f16x8 p = *(const f16x8*)(h2 + (size_t)r * 160 + c);
  f16x8 hv = *(const f16x8*)(hh + (size_t)r * SP + c);
  f16x8 ho;
#pragma unroll
  for (int j = 0; j < 8; ++j) {
    float v = fmaf((float)p[j], ab[c + j], ab[160 + c + j]);
    float hn = (float)hv[j] + fmaxf(v, 0.f);
    ho[j] = (f16)hn;
  }
  *(f16x8*)(hh + (size_t)r * SP + c) = ho;
}

// ---------------- fused layer-3 update + readout partials (no fence) ----------------
__global__ __launch_bounds__(256) void k_rdfuse(const f16* __restrict__ h2,
    const f16* __restrict__ hh, const float* __restrict__ st,
    const float* __restrict__ g, const float* __restrict__ bt,
    const int* __restrict__ gb, float* __restrict__ out16) {
  __shared__ float sa[148], sb[148], sacc[148];
  int t = threadIdx.x;
  if (t < 148) {
    float m = st[t] * (1.f / NN);
    float q = st[160 + t] * (1.f / NN);
    float iv = rsqrtf(q - m * m + EPSF);
    float gg = (t < HD) ? g[t] : 0.f;
    float bb = (t < HD) ? bt[t] : 0.f;
    float a = iv * gg;
    sa[t] = a;
    sb[t] = bb - m * a;
    sacc[t] = 0.f;
  }
  __syncthreads();
  int gr = blockIdx.x >> 4, chunk = blockIdx.x & 15;
  int lo = gb[gr], hi = gb[gr + 1];
  int w = t >> 6, lane = t & 63;
  f32x4 acc = (f32x4)0.f;
  if (lane < 37) {
    int c = lane * 4;
    for (int r = lo + chunk * 4 + w; r < hi; r += 64) {
      f16x4 p = *(const f16x4*)(h2 + (size_t)r * 160 + c);
      f16x4 hv = *(const f16x4*)(hh + (size_t)r * SP + c);
#pragma unroll
      for (int j = 0; j < 4; ++j) {
        float v = fmaf((float)p[j], sa[c + j], sb[c + j]);
        acc[j] += (float)hv[j] + fmaxf(v, 0.f);
      }
    }
    atomicAdd(&sacc[c + 0], acc[0]);
    atomicAdd(&sacc[c + 1], acc[1]);
    atomicAdd(&sacc[c + 2], acc[2]);
    atomicAdd(&sacc[c + 3], acc[3]);
  }
  __syncthreads();
  if (t < 148)
    out16[((size_t)chunk * NG + gr) * 148 + t] = sacc[t];
}

__global__ void k_rdiv(const int* __restrict__ gb, const float* __restrict__ out16,
                       float* __restrict__ out) {
  int g = blockIdx.x, c = threadIdx.x;
  if (c < HD) {
    float s = 0.f;
#pragma unroll
    for (int ch = 0; ch < 16; ++ch) s += out16[((size_t)ch * NG + g) * 148 + c];
    out[g * HD + c] = s / fmaxf((float)(gb[g + 1] - gb[g]), 1.f);
  }
}

extern "C" void kernel_launch(void* const* d_in, const int* in_sizes, int n_in,
                              void* d_out, int out_size, void* d_ws, size_t ws_size,
                              hipStream_t stream) {
  const float* X     = (const float*)d_in[0];
  const float* snorm = (const float*)d_in[1];
  const float* W_e   = (const float*)d_in[2];
  const float* b_e   = (const float*)d_in[3];
  const float* Wl[3]  = {(const float*)d_in[4], (const float*)d_in[8],  (const float*)d_in[12]};
  const float* bl[3]  = {(const float*)d_in[5], (const float*)d_in[9],  (const float*)d_in[13]};
  const float* gl[3]  = {(const float*)d_in[6], (const float*)d_in[10], (const float*)d_in[14]};
  const float* btl[3] = {(const float*)d_in[7], (const float*)d_in[11], (const float*)d_in[15]};
  const int* src = (const int*)d_in[16];
  const int* dst = (const int*)d_in[17];
  const int* gid = (const int*)d_in[18];
  float* out = (float*)d_out;

  char* p = (char*)d_ws;
  f16* hh    = (f16*)p;   p += sizeof(f16) * (size_t)NN * SP;          // 30.4 MB
  f16* aggt  = (f16*)p;   p += sizeof(f16) * (size_t)NRB * 20 * 128;   // 32 MB (h2, binD/S alias)
  f16* WtE   = (f16*)p;   p += sizeof(f16) * 10240;
  f16* Wt    = (f16*)p;   p += sizeof(f16) * 3 * 25600;
  float* bp  = (float*)p; p += sizeof(float) * 4 * 160;
  float* out16 = (float*)p; p += sizeof(float) * 16 * NG * 148;        // 2.42 MB
  float* stp = (float*)p; p += sizeof(float) * (size_t)GB * 320;       // 1.0 MB
  float* stsum = (float*)p; p += sizeof(float) * 320;
  float* ns  = (float*)p; p += sizeof(float) * NN;
  float* nd  = (float*)p; p += sizeof(float) * NN;
  int* offs = (int*)p; p += sizeof(int) * (NN + 1);
  int* csr  = (int*)p; p += sizeof(int) * NE;                          // 4 MB
  int* bhD  = (int*)p; p += sizeof(int) * NBIN * NCH;                  // 383 KB
  int* bhS  = (int*)p; p += sizeof(int) * NBIN * NCH;
  int* btotD = (int*)p; p += sizeof(int) * NBIN;
  int* btotS = (int*)p; p += sizeof(int) * NBIN;
  int* baseD = (int*)p; p += sizeof(int) * NBIN;
  int* baseS = (int*)p; p += sizeof(int) * NBIN;
  int* gb   = (int*)p; p += sizeof(int) * (NG + 1);

  int2* binD = (int2*)aggt;
  int*  binS = (int*)(aggt + (size_t)NE * 4);
  f16* h2 = aggt;

  k_A<<<NCH + PREPB, 256, 0, stream>>>(src, dst, bhD, bhS,
                                       W_e, Wl[0], Wl[1], Wl[2], b_e, bl[0], bl[1], bl[2],
                                       WtE, Wt, bp, gid, gb);
  k_p2<<<2 * NBIN, 512, 0, stream>>>(bhD, bhS, btotD, btotS);
  k_B<<<NCH + GB, 256, 0, stream>>>(src, dst, bhD, bhS, btotD, btotS,
                                    baseD, baseS, binD, binS, X, WtE, bp, hh);
  k_p56<<<2 * NBIN, 512, 0, stream>>>(binD, baseD, binS, baseS, offs, csr, nd, ns);

  for (int l = 0; l < 3; ++l) {
    k_pull<<<(NN * 64 + 255) / 256, 256, 0, stream>>>(hh, ns, nd, offs, csr, aggt);
    k_mfma<<<GB, 256, 0, stream>>>(aggt, Wt + l * 25600, bp + (l + 1) * 160,
                                   snorm, h2, stp);
    k_stred<<<320, 128, 0, stream>>>(stp, stsum);
    if (l < 2) {
      k_update<<<(NN * 19 + 255) / 256, 256, 0, stream>>>(h2, stsum, gl[l], btl[l], hh);
    } else {
      k_rdfuse<<<NG * 16, 256, 0, stream>>>(h2, hh, stsum, gl[2], btl[2], gb, out16);
    }
  }
  k_rdiv<<<NG, 192, 0, stream>>>(gb, out16, out);
}